// Round 2
// baseline (41865.500 us; speedup 1.0000x reference)
//
#include <hip/hip_runtime.h>
#include <stdint.h>

// ---------------------------------------------------------------------------
// Persistent-grid GRU, fence-free cross-WG pipeline.
//  - 4 batch-groups x 16 rows, 64 WGs/group (256 WGs ~ 1/CU).
//  - Weights live in REGISTERS (step-invariant bf16 hi/lo MFMA B-fragments).
//  - R2: SELF-SIGNALING DATA. Every exchanged word is a 64-bit
//    (tag<<32)|value stored with ONE relaxed agent atomic. Consumers poll
//    the exact words they need (gather == poll). Removes per-hop:
//    vmcnt(0) store-ack, flag hop, flag-poll->gather RTT, all-64 straggler
//    aggregation. Anti-WAW via one-way read-epoch stores (no ack needed).
//    Barriers are raw s_barrier + lgkmcnt(0) only: global stores are never
//    drained on the critical path (__syncthreads would vmcnt(0)-drain).
// ---------------------------------------------------------------------------

#define T_STEPS 2048
#define B_SZ    64
#define D_SZ    256
#define H_SZ    512
#define NGROUP  4
#define NWG     64
#define MB      16
#define CPW     6     // K-chunks (of 32) per wave; 4 waves * 6 = 24 = K 768

typedef __attribute__((ext_vector_type(8))) short  short8;
typedef __attribute__((ext_vector_type(4))) float  f32x4;
typedef unsigned long long u64;

__device__ __forceinline__ unsigned short f2bf(float v) {
  uint32_t u = __float_as_uint(v);
  return (unsigned short)((u + 0x7fffu + ((u >> 16) & 1u)) >> 16);   // RTNE
}
__device__ __forceinline__ float bf2f(unsigned short h) {
  return __uint_as_float(((uint32_t)h) << 16);
}
__device__ __forceinline__ void splitf(float v, short& hi, short& lo) {
  unsigned short h = f2bf(v);
  hi = (short)h;
  lo = (short)f2bf(v - bf2f(h));
}
__device__ __forceinline__ uint32_t packf(float v) {
  unsigned short h = f2bf(v);
  unsigned short l = f2bf(v - bf2f(h));
  return ((uint32_t)h << 16) | (uint32_t)l;
}
__device__ __forceinline__ float unpackf(uint32_t p) {
  return __uint_as_float(p & 0xffff0000u) + __uint_as_float(p << 16);
}

__device__ __forceinline__ uint32_t aload32(const uint32_t* p) {
  return __hip_atomic_load(p, __ATOMIC_RELAXED, __HIP_MEMORY_SCOPE_AGENT);
}
__device__ __forceinline__ void astore32(uint32_t* p, uint32_t v) {
  __hip_atomic_store(p, v, __ATOMIC_RELAXED, __HIP_MEMORY_SCOPE_AGENT);
}
__device__ __forceinline__ u64 aload64p(const u64* p) {
  return __hip_atomic_load(p, __ATOMIC_RELAXED, __HIP_MEMORY_SCOPE_AGENT);
}
__device__ __forceinline__ void astore64(u64* p, u64 v) {
  __hip_atomic_store(p, v, __ATOMIC_RELAXED, __HIP_MEMORY_SCOPE_AGENT);
}

// raw barrier: LDS ordering only; do NOT drain vmcnt (keeps publishes async)
__device__ __forceinline__ void lds_barrier() {
  asm volatile("s_waitcnt lgkmcnt(0)" ::: "memory");
  __builtin_amdgcn_s_barrier();
}

__global__ void __launch_bounds__(256, 1)
gru_persistent(const float* __restrict__ x, const float* __restrict__ h0,
               const float* __restrict__ Wz, const float* __restrict__ bz,
               const float* __restrict__ Wr, const float* __restrict__ br,
               const float* __restrict__ Wh, const float* __restrict__ bh,
               float* __restrict__ out,
               uint32_t* epoch,
               u64* h_pk, u64* rh_pk, u64* z_pk)
{
  __shared__ float partT[16 * 64];   // [kslice i][reg r][lane] transposed: conflict-free
  __shared__ float bias1s[16];
  __shared__ float bias2s[8];

  const int tid  = threadIdx.x;
  const int wv   = tid >> 6;
  const int lane = tid & 63;
  const int blk  = blockIdx.x;
  const int g    = blk >> 6;           // contiguous grouping: dispatch-order safe
  const int wid  = blk & 63;
  const int m0   = g * MB;
  const bool isZ = (wid < 32);
  const int c1   = (wid & 31) * 16;    // phase-1 column base (z or r gate)
  const int c2   = wid * 8;            // phase-2 column base (h gate)
  const float* W1 = isZ ? Wz : Wr;

  const int n     = lane & 15;         // MFMA fragment col / A-row-in-tile
  const int kq    = lane >> 4;         // k-quad
  const int bfrag = m0 + n;            // batch row this lane's A fragment holds
  const int m2    = kq * 4 + wv;       // C-layout row for this thread
  const int n2    = n;                 // C-layout col
  const int b2    = m0 + m2;

  uint32_t* my_ep = epoch + g * 64;    // per-WG read-epochs (anti-WAW)

  // ---- weights -> registers (B fragments, bf16 hi/lo; step-invariant) ----
  short8 w1h[CPW], w1l[CPW], w2h[CPW], w2l[CPW];
  #pragma unroll
  for (int i = 0; i < CPW; ++i) {
    const int ch = wv * CPW + i;
    #pragma unroll
    for (int j = 0; j < 8; ++j) {
      const int k = ch * 32 + kq * 8 + j;
      short hi, lo;
      splitf(W1[(size_t)k * H_SZ + c1 + n], hi, lo);
      w1h[i][j] = hi; w1l[i][j] = lo;
      float v = (n < 8) ? Wh[(size_t)k * H_SZ + c2 + n] : 0.f;
      splitf(v, hi, lo);
      w2h[i][j] = hi; w2l[i][j] = lo;
    }
  }
  if (tid < 16)      bias1s[tid] = isZ ? bz[c1 + tid] : br[c1 + tid];
  else if (tid < 24) bias2s[tid - 16] = bh[c2 + (tid - 16)];
  __syncthreads();   // one-time init barrier (full drain fine here)

  // own recurrent column kept as exact f32 register chain
  float hreg = (n2 < 8) ? h0[(size_t)b2 * H_SZ + c2 + n2] : 0.f;

  int cap = 1 << 20;

  #pragma unroll 1
  for (int t = 0; t < T_STEPS; ++t) {
    short8 ah[CPW], al[CPW];

    // ---- x fragments (chunks 0..7): independent of h, do before gather ----
    #pragma unroll
    for (int i = 0; i < CPW; ++i) {
      const int ch = wv * CPW + i;
      if (ch < 8) {
        const float* xp = x + ((size_t)t * B_SZ + bfrag) * D_SZ + ch * 32 + kq * 8;
        float4 f0 = *(const float4*)xp;
        float4 f1 = *(const float4*)(xp + 4);
        float f[8] = {f0.x, f0.y, f0.z, f0.w, f1.x, f1.y, f1.z, f1.w};
        #pragma unroll
        for (int j = 0; j < 8; ++j) { short hi, lo; splitf(f[j], hi, lo); ah[i][j] = hi; al[i][j] = lo; }
      }
    }

    // ---- phase-1 gather: tagged h words (gather IS the poll) ----
    uint32_t hpv = 0; float hp0 = 0.f;
    if (t > 0) {
      const uint32_t tgt = (uint32_t)t;       // h(t-1) carries tag t
      int guard = 0;
      for (;;) {
        uint32_t mt = 0xffffffffu;
        if (!isZ) {
          u64 q = aload64p(h_pk + (size_t)b2 * H_SZ + c1 + n2);
          hpv = (uint32_t)q;
          uint32_t tg = (uint32_t)(q >> 32); mt = tg < mt ? tg : mt;
        }
        #pragma unroll
        for (int i = 0; i < CPW; ++i) {
          const int ch = wv * CPW + i;
          if (ch >= 8) {
            const int kh = ch * 32 - 256 + kq * 8;
            const u64* hp = h_pk + (size_t)bfrag * H_SZ + kh;
            #pragma unroll
            for (int j = 0; j < 8; ++j) {
              u64 q = aload64p(hp + j);
              uint32_t tg = (uint32_t)(q >> 32); mt = tg < mt ? tg : mt;
              uint32_t v = (uint32_t)q;
              ah[i][j] = (short)(v >> 16); al[i][j] = (short)(v & 0xffffu);
            }
          }
        }
        if (__all((int)(mt >= tgt))) break;
        if (++guard > cap) { cap = 256; break; }   // degrade, never deadlock
        __builtin_amdgcn_s_sleep(1);
      }
    } else {
      if (!isZ) hp0 = h0[(size_t)b2 * H_SZ + c1 + n2];
      #pragma unroll
      for (int i = 0; i < CPW; ++i) {
        const int ch = wv * CPW + i;
        if (ch >= 8) {
          const int kh = ch * 32 - 256 + kq * 8;
          const float* hp = h0 + (size_t)bfrag * H_SZ + kh;
          float4 f0 = *(const float4*)hp;
          float4 f1 = *(const float4*)(hp + 4);
          float f[8] = {f0.x, f0.y, f0.z, f0.w, f1.x, f1.y, f1.z, f1.w};
          #pragma unroll
          for (int j = 0; j < 8; ++j) { short hi, lo; splitf(f[j], hi, lo); ah[i][j] = hi; al[i][j] = lo; }
        }
      }
    }

    // ---- phase-1 MFMA: [16,768] @ [768,16], 3-term hi/lo split ----
    {
      f32x4 acc = {0.f, 0.f, 0.f, 0.f};
      #pragma unroll
      for (int i = 0; i < CPW; ++i) {
        acc = __builtin_amdgcn_mfma_f32_16x16x32_bf16(ah[i], w1h[i], acc, 0, 0, 0);
        acc = __builtin_amdgcn_mfma_f32_16x16x32_bf16(al[i], w1h[i], acc, 0, 0, 0);
        acc = __builtin_amdgcn_mfma_f32_16x16x32_bf16(ah[i], w1l[i], acc, 0, 0, 0);
      }
      #pragma unroll
      for (int r = 0; r < 4; ++r) partT[(wv * 4 + r) * 64 + lane] = acc[r];
    }
    lds_barrier();

    // read-epoch: this WG's h(t-1) loads are complete (values in regs).
    // One-way store, no ack — asserts READS done, not data ready.
    if (tid == 0) astore32(my_ep + wid, (uint32_t)(t + 1));

    // ---- reduce K-slices, activate, publish tagged z / r*h ----
    {
      float s = partT[(0 + wv) * 64 + lane] + partT[(4 + wv) * 64 + lane]
              + partT[(8 + wv) * 64 + lane] + partT[(12 + wv) * 64 + lane] + bias1s[n2];
      float sg = 1.f / (1.f + __expf(-s));
      const u64 tagw = ((u64)(uint32_t)(t + 1)) << 32;
      if (isZ) {
        astore64(z_pk + (size_t)b2 * H_SZ + c1 + n2, tagw | (u64)__float_as_uint(sg));
      } else {
        float hp = (t > 0) ? unpackf(hpv) : hp0;
        astore64(rh_pk + (size_t)b2 * H_SZ + c1 + n2, tagw | (u64)packf(sg * hp));
      }
    }
    lds_barrier();   // partT reuse guard (no vmcnt drain: publish stays async)

    // ---- phase-2 gather: tagged z word + rh fragments ----
    uint32_t zu = 0;
    {
      const uint32_t tgt2 = (uint32_t)(t + 1);
      int guard = 0;
      for (;;) {
        uint32_t mt = 0xffffffffu;
        u64 zq = 0;
        if (n2 < 8) {
          zq = aload64p(z_pk + (size_t)b2 * H_SZ + c2 + n2);
          uint32_t tg = (uint32_t)(zq >> 32); mt = tg < mt ? tg : mt;
        }
        #pragma unroll
        for (int i = 0; i < CPW; ++i) {
          const int ch = wv * CPW + i;
          if (ch >= 8) {
            const int kh = ch * 32 - 256 + kq * 8;
            const u64* rp = rh_pk + (size_t)bfrag * H_SZ + kh;
            #pragma unroll
            for (int j = 0; j < 8; ++j) {
              u64 q = aload64p(rp + j);
              uint32_t tg = (uint32_t)(q >> 32); mt = tg < mt ? tg : mt;
              uint32_t v = (uint32_t)q;
              ah[i][j] = (short)(v >> 16); al[i][j] = (short)(v & 0xffffu);
            }
          }
        }
        if (__all((int)(mt >= tgt2))) { zu = (uint32_t)zq; break; }
        if (++guard > cap) { cap = 256; zu = (uint32_t)zq; break; }
        __builtin_amdgcn_s_sleep(1);
      }
    }

    // preload epochs (checked after MFMA — off critical path when on time)
    uint32_t ep = aload32(my_ep + lane);

    // ---- phase-2 MFMA: h-candidate slice (8 live cols, 8 zero-padded) ----
    {
      f32x4 acc = {0.f, 0.f, 0.f, 0.f};
      #pragma unroll
      for (int i = 0; i < CPW; ++i) {
        acc = __builtin_amdgcn_mfma_f32_16x16x32_bf16(ah[i], w2h[i], acc, 0, 0, 0);
        acc = __builtin_amdgcn_mfma_f32_16x16x32_bf16(al[i], w2h[i], acc, 0, 0, 0);
        acc = __builtin_amdgcn_mfma_f32_16x16x32_bf16(ah[i], w2l[i], acc, 0, 0, 0);
      }
      #pragma unroll
      for (int r = 0; r < 4; ++r) partT[(wv * 4 + r) * 64 + lane] = acc[r];
    }
    lds_barrier();

    // ---- reduce, tanh, h-update (exact f32 register chain) ----
    float hn = 0.f; const bool live = (n2 < 8);
    if (live) {
      float s = partT[(0 + wv) * 64 + lane] + partT[(4 + wv) * 64 + lane]
              + partT[(8 + wv) * 64 + lane] + partT[(12 + wv) * 64 + lane] + bias2s[n2];
      float e  = __expf(2.f * s);
      float ht = 1.f - 2.f / (e + 1.f);
      float zf = __uint_as_float(zu);
      hn = (1.f - zf) * hreg + zf * ht;
      hreg = hn;
    }

    // anti-WAW: all 64 WGs of group must have finished reading h(t-1)
    // before we overwrite with h(t). Usually satisfied long ago.
    {
      int guard = 0;
      while (!__all((int)(ep >= (uint32_t)(t + 1)))) {
        if (++guard > cap) { cap = 256; break; }
        __builtin_amdgcn_s_sleep(1);
        ep = aload32(my_ep + lane);
      }
    }

    if (live) {
      const u64 tagw = ((u64)(uint32_t)(t + 1)) << 32;
      astore64(h_pk + (size_t)b2 * H_SZ + c2 + n2, tagw | (u64)packf(hn));
      // HBM history write after recurrent publish: off the critical path
      __builtin_nontemporal_store(hn, out + ((size_t)t * B_SZ + b2) * H_SZ + c2 + n2);
    }
    lds_barrier();   // partT guard for next step's phase-1
  }
}

extern "C" void kernel_launch(void* const* d_in, const int* in_sizes, int n_in,
                              void* d_out, int out_size, void* d_ws, size_t ws_size,
                              hipStream_t stream) {
  const float* x  = (const float*)d_in[0];
  const float* h0 = (const float*)d_in[1];
  const float* Wz = (const float*)d_in[2];
  const float* bz = (const float*)d_in[3];
  const float* Wr = (const float*)d_in[4];
  const float* br = (const float*)d_in[5];
  const float* Wh = (const float*)d_in[6];
  const float* bh = (const float*)d_in[7];
  float* out = (float*)d_out;

  char* ws = (char*)d_ws;
  uint32_t* epoch = (uint32_t*)(ws + 0);          // [4][64] read-epochs
  u64* h_pk  = (u64*)(ws + 4096);                 // [64][512] (tag<<32)|bf16hi|lo
  u64* rh_pk = (u64*)(ws + 4096 + 262144);        // [64][512] tagged packed
  u64* z_pk  = (u64*)(ws + 4096 + 524288);        // [64][512] (tag<<32)|f32

  // zero epochs AND plane tags (tag 0 = "no step published yet")
  hipMemsetAsync(d_ws, 0, 4096 + 3 * 262144, stream);
  gru_persistent<<<dim3(NGROUP * NWG), dim3(256), 0, stream>>>(
      x, h0, Wz, bz, Wr, br, Wh, bh, out,
      epoch, h_pk, rh_pk, z_pk);
}

// Round 4
// 36188.928 us; speedup vs baseline: 1.1569x; 1.1569x over previous
//
#include <hip/hip_runtime.h>
#include <stdint.h>

// ---------------------------------------------------------------------------
// Persistent-grid GRU, fence-free cross-WG pipeline (R4 = R1 + two changes).
//  - 4 batch-groups x 16 rows, 64 WGs/group (256 WGs ~ 1/CU).
//  - Weights live in REGISTERS (step-invariant bf16 hi/lo MFMA B-fragments).
//  - R4a: TAGGED 64-bit exchange words ((tag<<32)|payload). Producer raises
//    its per-WG flag WITHOUT a vmcnt(0) store-ack (deletes 1 RTT/hop);
//    consumer validates tags after the flag-gated gather and re-gathers only
//    on rare stragglers (validation replaces the ack, not the wait).
//  - R4b: only WAVE 0 polls flags; waves 1-3 park at a raw s_barrier
//    (4x less poll traffic -> less LLC hot-line contention -> lower RTT).
//  - No vmcnt drain anywhere in the loop: barriers are lgkmcnt-only.
// ---------------------------------------------------------------------------

#define T_STEPS 2048
#define B_SZ    64
#define D_SZ    256
#define H_SZ    512
#define NGROUP  4
#define NWG     64
#define MB      16
#define CPW     6     // K-chunks (of 32) per wave; 4 waves * 6 = 24 = K 768

typedef __attribute__((ext_vector_type(8))) short  short8;
typedef __attribute__((ext_vector_type(4))) float  f32x4;
typedef unsigned long long u64;

__device__ __forceinline__ unsigned short f2bf(float v) {
  uint32_t u = __float_as_uint(v);
  return (unsigned short)((u + 0x7fffu + ((u >> 16) & 1u)) >> 16);   // RTNE
}
__device__ __forceinline__ float bf2f(unsigned short h) {
  return __uint_as_float(((uint32_t)h) << 16);
}
__device__ __forceinline__ void splitf(float v, short& hi, short& lo) {
  unsigned short h = f2bf(v);
  hi = (short)h;
  lo = (short)f2bf(v - bf2f(h));
}
__device__ __forceinline__ uint32_t packf(float v) {
  unsigned short h = f2bf(v);
  unsigned short l = f2bf(v - bf2f(h));
  return ((uint32_t)h << 16) | (uint32_t)l;
}
__device__ __forceinline__ float unpackf(uint32_t p) {
  return __uint_as_float(p & 0xffff0000u) + __uint_as_float(p << 16);
}

__device__ __forceinline__ uint32_t aload32(const uint32_t* p) {
  return __hip_atomic_load(p, __ATOMIC_RELAXED, __HIP_MEMORY_SCOPE_AGENT);
}
__device__ __forceinline__ void astore32(uint32_t* p, uint32_t v) {
  __hip_atomic_store(p, v, __ATOMIC_RELAXED, __HIP_MEMORY_SCOPE_AGENT);
}
__device__ __forceinline__ u64 aload64(const u64* p) {
  return __hip_atomic_load(p, __ATOMIC_RELAXED, __HIP_MEMORY_SCOPE_AGENT);
}
__device__ __forceinline__ void astore64(u64* p, u64 v) {
  __hip_atomic_store(p, v, __ATOMIC_RELAXED, __HIP_MEMORY_SCOPE_AGENT);
}

// raw barrier: LDS ordering only; never drains vmcnt (publishes stay async)
__device__ __forceinline__ void lds_barrier() {
  asm volatile("s_waitcnt lgkmcnt(0)" ::: "memory");
  __builtin_amdgcn_s_barrier();
}

// Lane-parallel flag poll: lane i watches flags[i]; wave-uniform exit.
// Called by wave 0 only (R4b).
__device__ __forceinline__ void poll_flags(const uint32_t* fl, uint32_t tgt,
                                           int lane, int& cap) {
  int guard = 0;
  for (;;) {
    uint32_t v = aload32(fl + lane);
    if (__all((int)(v >= tgt))) break;
    if (++guard > cap) { cap = 256; break; }   // degrade, never deadlock
    __builtin_amdgcn_s_sleep(1);
  }
}

__global__ void __launch_bounds__(256, 1)
gru_persistent(const float* __restrict__ x, const float* __restrict__ h0,
               const float* __restrict__ Wz, const float* __restrict__ bz,
               const float* __restrict__ Wr, const float* __restrict__ br,
               const float* __restrict__ Wh, const float* __restrict__ bh,
               float* __restrict__ out,
               uint32_t* zr_flg, uint32_t* h_flg,
               u64* h_pk, u64* rh_pk, u64* z_pk)
{
  __shared__ float partT[16 * 64];   // [kslice i][reg r][lane] transposed: conflict-free
  __shared__ float bias1s[16];
  __shared__ float bias2s[8];

  const int tid  = threadIdx.x;
  const int wv   = tid >> 6;
  const int lane = tid & 63;
  const int blk  = blockIdx.x;
  const int g    = blk >> 6;           // contiguous grouping: dispatch-order safe
  const int wid  = blk & 63;
  const int m0   = g * MB;
  const bool isZ = (wid < 32);
  const int c1   = (wid & 31) * 16;    // phase-1 column base (z or r gate)
  const int c2   = wid * 8;            // phase-2 column base (h gate)
  const float* W1 = isZ ? Wz : Wr;

  const int n     = lane & 15;         // MFMA fragment col / A-row-in-tile
  const int kq    = lane >> 4;         // k-quad
  const int bfrag = m0 + n;            // batch row this lane's A fragment holds
  const int m2    = kq * 4 + wv;       // C-layout row for this thread
  const int n2    = n;                 // C-layout col
  const int b2    = m0 + m2;

  uint32_t* my_zr = zr_flg + g * 64;   // per-WG flag words, 256 B per group
  uint32_t* my_h  = h_flg  + g * 64;

  // ---- weights -> registers (B fragments, bf16 hi/lo; step-invariant) ----
  short8 w1h[CPW], w1l[CPW], w2h[CPW], w2l[CPW];
  #pragma unroll
  for (int i = 0; i < CPW; ++i) {
    const int ch = wv * CPW + i;
    #pragma unroll
    for (int j = 0; j < 8; ++j) {
      const int k = ch * 32 + kq * 8 + j;
      short hi, lo;
      splitf(W1[(size_t)k * H_SZ + c1 + n], hi, lo);
      w1h[i][j] = hi; w1l[i][j] = lo;
      float v = (n < 8) ? Wh[(size_t)k * H_SZ + c2 + n] : 0.f;
      splitf(v, hi, lo);
      w2h[i][j] = hi; w2l[i][j] = lo;
    }
  }
  if (tid < 16)      bias1s[tid] = isZ ? bz[c1 + tid] : br[c1 + tid];
  else if (tid < 24) bias2s[tid - 16] = bh[c2 + (tid - 16)];
  __syncthreads();   // one-time init barrier (full drain fine here)

  // own recurrent column kept as exact f32 register chain
  float hreg = (n2 < 8) ? h0[(size_t)b2 * H_SZ + c2 + n2] : 0.f;

  int cap = 1 << 20;

  #pragma unroll 1
  for (int t = 0; t < T_STEPS; ++t) {
    short8 ah[CPW], al[CPW];

    // ---- x fragments (chunks 0..7): independent of h, before any wait ----
    #pragma unroll
    for (int i = 0; i < CPW; ++i) {
      const int ch = wv * CPW + i;
      if (ch < 8) {
        const float* xp = x + ((size_t)t * B_SZ + bfrag) * D_SZ + ch * 32 + kq * 8;
        float4 f0 = *(const float4*)xp;
        float4 f1 = *(const float4*)(xp + 4);
        float f[8] = {f0.x, f0.y, f0.z, f0.w, f1.x, f1.y, f1.z, f1.w};
        #pragma unroll
        for (int j = 0; j < 8; ++j) { short hi, lo; splitf(f[j], hi, lo); ah[i][j] = hi; al[i][j] = lo; }
      }
    }

    // ---- wait for h(t-1): wave 0 polls flags, others park at barrier ----
    uint32_t hpu = 0; float hp0 = 0.f;
    if (t > 0) {
      if (wv == 0) poll_flags(my_h, (uint32_t)t, lane, cap);
      lds_barrier();                       // broadcast "ready" to waves 1-3

      // ---- validated gather: h fragments + r-gate's own h word ----
      const uint32_t tgt = (uint32_t)t;    // h(t-1) carries tag t
      int guard = 0;
      for (;;) {
        uint32_t mt = 0xffffffffu;
        if (!isZ) {
          u64 q = aload64(h_pk + (size_t)b2 * H_SZ + c1 + n2);
          hpu = (uint32_t)q;
          uint32_t tg = (uint32_t)(q >> 32); mt = tg < mt ? tg : mt;
        }
        #pragma unroll
        for (int i = 0; i < CPW; ++i) {
          const int ch = wv * CPW + i;
          if (ch >= 8) {
            const u64* hp = h_pk + (size_t)bfrag * H_SZ + (ch * 32 - 256) + kq * 8;
            #pragma unroll
            for (int j = 0; j < 8; ++j) {
              u64 q = aload64(hp + j);
              uint32_t tg = (uint32_t)(q >> 32); mt = tg < mt ? tg : mt;
              uint32_t v = (uint32_t)q;
              ah[i][j] = (short)(v >> 16); al[i][j] = (short)(v & 0xffffu);
            }
          }
        }
        if (__all((int)(mt >= tgt))) break;          // steady state: 1 pass
        if (++guard > cap) { cap = 256; break; }     // loud-fail path
        __builtin_amdgcn_s_sleep(1);
      }
    } else {
      if (!isZ) hp0 = h0[(size_t)b2 * H_SZ + c1 + n2];
      #pragma unroll
      for (int i = 0; i < CPW; ++i) {
        const int ch = wv * CPW + i;
        if (ch >= 8) {
          const float* hp = h0 + (size_t)bfrag * H_SZ + (ch * 32 - 256) + kq * 8;
          float4 f0 = *(const float4*)hp;
          float4 f1 = *(const float4*)(hp + 4);
          float f[8] = {f0.x, f0.y, f0.z, f0.w, f1.x, f1.y, f1.z, f1.w};
          #pragma unroll
          for (int j = 0; j < 8; ++j) { short hi, lo; splitf(f[j], hi, lo); ah[i][j] = hi; al[i][j] = lo; }
        }
      }
    }

    // ---- phase-1 MFMA: [16,768] @ [768,16], 3-term hi/lo split ----
    {
      f32x4 acc = {0.f, 0.f, 0.f, 0.f};
      #pragma unroll
      for (int i = 0; i < CPW; ++i) {
        acc = __builtin_amdgcn_mfma_f32_16x16x32_bf16(ah[i], w1h[i], acc, 0, 0, 0);
        acc = __builtin_amdgcn_mfma_f32_16x16x32_bf16(al[i], w1h[i], acc, 0, 0, 0);
        acc = __builtin_amdgcn_mfma_f32_16x16x32_bf16(ah[i], w1l[i], acc, 0, 0, 0);
      }
      #pragma unroll
      for (int r = 0; r < 4; ++r) partT[(wv * 4 + r) * 64 + lane] = acc[r];
    }
    lds_barrier();

    // ---- reduce K-slices, activate, publish tagged z / r*h (NO ack) ----
    {
      float s = partT[(0 + wv) * 64 + lane] + partT[(4 + wv) * 64 + lane]
              + partT[(8 + wv) * 64 + lane] + partT[(12 + wv) * 64 + lane] + bias1s[n2];
      float sg = 1.f / (1.f + __expf(-s));
      const u64 tagw = ((u64)(uint32_t)(t + 1)) << 32;
      if (isZ) {
        astore64(z_pk + (size_t)b2 * H_SZ + c1 + n2, tagw | (u64)__float_as_uint(sg));
      } else {
        float hp = (t > 0) ? unpackf(hpu) : hp0;
        astore64(rh_pk + (size_t)b2 * H_SZ + c1 + n2, tagw | (u64)packf(sg * hp));
      }
    }
    lds_barrier();   // partT guard + all publishes issued before flag raise
    if (tid == 0) astore32(my_zr + wid, (uint32_t)(t + 1));   // fire-and-forget

    // ---- wait for all z / r*h of step t ----
    if (wv == 0) poll_flags(my_zr, (uint32_t)(t + 1), lane, cap);
    lds_barrier();

    // ---- validated gather: z word + rh fragments (tag t+1) ----
    uint32_t zu = 0;
    {
      const uint32_t tgt2 = (uint32_t)(t + 1);
      int guard = 0;
      for (;;) {
        uint32_t mt = 0xffffffffu;
        if (n2 < 8) {
          u64 zq = aload64(z_pk + (size_t)b2 * H_SZ + c2 + n2);
          zu = (uint32_t)zq;
          uint32_t tg = (uint32_t)(zq >> 32); mt = tg < mt ? tg : mt;
        }
        #pragma unroll
        for (int i = 0; i < CPW; ++i) {
          const int ch = wv * CPW + i;
          if (ch >= 8) {
            const u64* rp = rh_pk + (size_t)bfrag * H_SZ + (ch * 32 - 256) + kq * 8;
            #pragma unroll
            for (int j = 0; j < 8; ++j) {
              u64 q = aload64(rp + j);
              uint32_t tg = (uint32_t)(q >> 32); mt = tg < mt ? tg : mt;
              uint32_t v = (uint32_t)q;
              ah[i][j] = (short)(v >> 16); al[i][j] = (short)(v & 0xffffu);
            }
          }
        }
        if (__all((int)(mt >= tgt2))) break;
        if (++guard > cap) { cap = 256; break; }
        __builtin_amdgcn_s_sleep(1);
      }
    }

    // ---- phase-2 MFMA: h-candidate slice (8 live cols, 8 zero-padded) ----
    {
      f32x4 acc = {0.f, 0.f, 0.f, 0.f};
      #pragma unroll
      for (int i = 0; i < CPW; ++i) {
        acc = __builtin_amdgcn_mfma_f32_16x16x32_bf16(ah[i], w2h[i], acc, 0, 0, 0);
        acc = __builtin_amdgcn_mfma_f32_16x16x32_bf16(al[i], w2h[i], acc, 0, 0, 0);
        acc = __builtin_amdgcn_mfma_f32_16x16x32_bf16(ah[i], w2l[i], acc, 0, 0, 0);
      }
      #pragma unroll
      for (int r = 0; r < 4; ++r) partT[(wv * 4 + r) * 64 + lane] = acc[r];
    }
    lds_barrier();

    // ---- reduce, tanh, h-update (exact f32 register chain), publish h ----
    float hn = 0.f; const bool live = (n2 < 8);
    if (live) {
      float s = partT[(0 + wv) * 64 + lane] + partT[(4 + wv) * 64 + lane]
              + partT[(8 + wv) * 64 + lane] + partT[(12 + wv) * 64 + lane] + bias2s[n2];
      float e  = __expf(2.f * s);
      float ht = 1.f - 2.f / (e + 1.f);
      float zf = __uint_as_float(zu);
      hn = (1.f - zf) * hreg + zf * ht;
      hreg = hn;
      const u64 tagw = ((u64)(uint32_t)(t + 1)) << 32;
      astore64(h_pk + (size_t)b2 * H_SZ + c2 + n2, tagw | (u64)packf(hn));
    }
    lds_barrier();   // partT guard + publishes issued before flag raise
    if (tid == 0) astore32(my_h + wid, (uint32_t)(t + 1));    // release step t

    // HBM history write after release: off the critical path
    if (live)
      __builtin_nontemporal_store(hn, out + ((size_t)t * B_SZ + b2) * H_SZ + c2 + n2);
  }
}

extern "C" void kernel_launch(void* const* d_in, const int* in_sizes, int n_in,
                              void* d_out, int out_size, void* d_ws, size_t ws_size,
                              hipStream_t stream) {
  const float* x  = (const float*)d_in[0];
  const float* h0 = (const float*)d_in[1];
  const float* Wz = (const float*)d_in[2];
  const float* bz = (const float*)d_in[3];
  const float* Wr = (const float*)d_in[4];
  const float* br = (const float*)d_in[5];
  const float* Wh = (const float*)d_in[6];
  const float* bh = (const float*)d_in[7];
  float* out = (float*)d_out;

  char* ws = (char*)d_ws;
  uint32_t* zr_flg = (uint32_t*)(ws + 0);        // [4][64] per-WG release flags
  uint32_t* h_flg  = (uint32_t*)(ws + 16384);    // [4][64] per-WG release flags
  u64* h_pk  = (u64*)(ws + 32768);               // [64][512] (tag<<32)|bf16hi|lo
  u64* rh_pk = (u64*)(ws + 32768 + 262144);      // [64][512] tagged packed
  u64* z_pk  = (u64*)(ws + 32768 + 524288);      // [64][512] (tag<<32)|f32

  // zero flags AND plane tags (tag 0 = "nothing published"; also clears
  // stale tags from previous bench iterations reusing this workspace)
  hipMemsetAsync(d_ws, 0, 32768 + 3 * 262144, stream);
  gru_persistent<<<dim3(NGROUP * NWG), dim3(256), 0, stream>>>(
      x, h0, Wz, bz, Wr, br, Wh, bh, out,
      zr_flg, h_flg, h_pk, rh_pk, z_pk);
}

// Round 5
// 25673.157 us; speedup vs baseline: 1.6307x; 1.4096x over previous
//
#include <hip/hip_runtime.h>
#include <stdint.h>

// ---------------------------------------------------------------------------
// Persistent-grid GRU, fence-free cross-WG pipeline (R5: role-split).
//  - 4 batch-groups x 16 rows, 64 WGs/group.
//  - ROLE SPLIT: per group, WGs 0-31 = GATE (own 16 cols of BOTH z and r;
//    wait only for h), WGs 32-63 = CAND (own 16 candidate cols; wait only
//    for rh; keep exact-f32 hreg chain; blend with z from z-plane).
//    One wait per WG per step (was two): poll traffic halved, flag fan-in
//    halved (32 flags = 1 cache line), straggler window shrinks.
//  - X-PRECOMPUTE: each wave's 2 x-chunks MFMA'd into the accumulator
//    BEFORE the poll; post-arrival work = 4 h-chunk gathers + 12 MFMAs.
//  - Transport byte-identical to R1 (proven): packed (bf16hi<<16|lo) u32
//    planes, f32 z-plane, per-thread vmcnt(0) ack, per-WG flags,
//    lane-parallel all-wave polls, lgkmcnt-only barriers.
// ---------------------------------------------------------------------------

#define T_STEPS 2048
#define B_SZ    64
#define D_SZ    256
#define H_SZ    512
#define NGROUP  4
#define NWG     64
#define MB      16

typedef __attribute__((ext_vector_type(8))) short  short8;
typedef __attribute__((ext_vector_type(4))) float  f32x4;
typedef unsigned long long u64;

__device__ __forceinline__ unsigned short f2bf(float v) {
  uint32_t u = __float_as_uint(v);
  return (unsigned short)((u + 0x7fffu + ((u >> 16) & 1u)) >> 16);   // RTNE
}
__device__ __forceinline__ float bf2f(unsigned short h) {
  return __uint_as_float(((uint32_t)h) << 16);
}
__device__ __forceinline__ void splitf(float v, short& hi, short& lo) {
  unsigned short h = f2bf(v);
  hi = (short)h;
  lo = (short)f2bf(v - bf2f(h));
}
__device__ __forceinline__ uint32_t packf(float v) {
  unsigned short h = f2bf(v);
  unsigned short l = f2bf(v - bf2f(h));
  return ((uint32_t)h << 16) | (uint32_t)l;
}
__device__ __forceinline__ float unpackf(uint32_t p) {
  return __uint_as_float(p & 0xffff0000u) + __uint_as_float(p << 16);
}

__device__ __forceinline__ uint32_t aload32(const uint32_t* p) {
  return __hip_atomic_load(p, __ATOMIC_RELAXED, __HIP_MEMORY_SCOPE_AGENT);
}
__device__ __forceinline__ u64 aload64(const uint32_t* p) {
  return __hip_atomic_load((const unsigned long long*)p, __ATOMIC_RELAXED,
                           __HIP_MEMORY_SCOPE_AGENT);
}
__device__ __forceinline__ void astore32(uint32_t* p, uint32_t v) {
  __hip_atomic_store(p, v, __ATOMIC_RELAXED, __HIP_MEMORY_SCOPE_AGENT);
}

// raw barrier: LDS ordering only (vmcnt acks are done per-thread explicitly)
__device__ __forceinline__ void lds_barrier() {
  asm volatile("s_waitcnt lgkmcnt(0)" ::: "memory");
  __builtin_amdgcn_s_barrier();
}

// Lane-parallel poll over 32 per-WG flags (lanes 32-63 mirror 0-31).
__device__ __forceinline__ void poll_flags(const uint32_t* fl, uint32_t tgt,
                                           int lane, int& cap) {
  int guard = 0;
  for (;;) {
    uint32_t v = aload32(fl + (lane & 31));
    if (__all((int)(v >= tgt))) break;
    if (++guard > cap) { cap = 256; break; }   // degrade, never deadlock
    __builtin_amdgcn_s_sleep(1);
  }
}

__global__ void __launch_bounds__(256, 1)
gru_roles(const float* __restrict__ x, const float* __restrict__ h0,
          const float* __restrict__ Wz, const float* __restrict__ bz,
          const float* __restrict__ Wr, const float* __restrict__ br,
          const float* __restrict__ Wh, const float* __restrict__ bh,
          float* __restrict__ out,
          uint32_t* rh_flg, uint32_t* h_flg,
          uint32_t* h_pk, uint32_t* rh_pk, uint32_t* z_pk)
{
  __shared__ float partTa[16 * 64];
  __shared__ float partTb[16 * 64];

  const int tid  = threadIdx.x;
  const int wv   = tid >> 6;
  const int lane = tid & 63;
  const int blk  = blockIdx.x;
  const int g    = blk >> 6;           // contiguous grouping: dispatch-order safe
  const int wid  = blk & 63;
  const int m0   = g * MB;
  const bool isGate = (wid < 32);

  const int n     = lane & 15;         // MFMA fragment col / A-row-in-tile
  const int kq    = lane >> 4;         // k-quad
  const int bfrag = m0 + n;            // batch row this lane's A fragment holds
  const int m2    = kq * 4 + wv;       // C-layout row for this thread
  const int n2    = n;                 // C-layout col
  const int b2    = m0 + m2;

  uint32_t* frh = rh_flg + g * 32;     // raised by gate-WGs
  uint32_t* fh  = h_flg  + g * 32;     // raised by cand-WGs

  // chunk->wave map: wave wv owns x-chunks {2wv, 2wv+1}, h-chunks {8+4wv..11+4wv}
  // local l: 0,1 -> x; 2..5 -> h.
  int lch[6];
  lch[0] = 2 * wv; lch[1] = 2 * wv + 1;
  #pragma unroll
  for (int l = 2; l < 6; ++l) lch[l] = 8 + 4 * wv + (l - 2);

  int cap = 1 << 20;

  if (isGate) {
    // =================== GATE: 16 cols of z AND r ===================
    const int c1  = wid * 16;
    const int col = c1 + n;

    short8 wzh[6], wzl[6], wrh_[6], wrl_[6];
    #pragma unroll
    for (int l = 0; l < 6; ++l) {
      #pragma unroll
      for (int j = 0; j < 8; ++j) {
        const int k = lch[l] * 32 + kq * 8 + j;
        short hi, lo;
        splitf(Wz[(size_t)k * H_SZ + col], hi, lo); wzh[l][j] = hi; wzl[l][j] = lo;
        splitf(Wr[(size_t)k * H_SZ + col], hi, lo); wrh_[l][j] = hi; wrl_[l][j] = lo;
      }
    }
    const float bzv = bz[col];
    const float brv = br[col];

    #pragma unroll 1
    for (int t = 0; t < T_STEPS; ++t) {
      // ---- x-part precompute (before poll; acc carries over) ----
      f32x4 aZ = {0.f, 0.f, 0.f, 0.f};
      f32x4 aR = {0.f, 0.f, 0.f, 0.f};
      #pragma unroll
      for (int l = 0; l < 2; ++l) {
        const float* xp = x + ((size_t)t * B_SZ + bfrag) * D_SZ + lch[l] * 32 + kq * 8;
        float4 f0 = *(const float4*)xp;
        float4 f1 = *(const float4*)(xp + 4);
        float f[8] = {f0.x, f0.y, f0.z, f0.w, f1.x, f1.y, f1.z, f1.w};
        short8 xh, xl;
        #pragma unroll
        for (int j = 0; j < 8; ++j) { short hi, lo; splitf(f[j], hi, lo); xh[j] = hi; xl[j] = lo; }
        aZ = __builtin_amdgcn_mfma_f32_16x16x32_bf16(xh, wzh[l], aZ, 0, 0, 0);
        aZ = __builtin_amdgcn_mfma_f32_16x16x32_bf16(xl, wzh[l], aZ, 0, 0, 0);
        aZ = __builtin_amdgcn_mfma_f32_16x16x32_bf16(xh, wzl[l], aZ, 0, 0, 0);
        aR = __builtin_amdgcn_mfma_f32_16x16x32_bf16(xh, wrh_[l], aR, 0, 0, 0);
        aR = __builtin_amdgcn_mfma_f32_16x16x32_bf16(xl, wrh_[l], aR, 0, 0, 0);
        aR = __builtin_amdgcn_mfma_f32_16x16x32_bf16(xh, wrl_[l], aR, 0, 0, 0);
      }

      // ---- wait for h(t-1), gather 4 h-chunks, finish MFMAs ----
      float hval;
      if (t > 0) {
        poll_flags(fh, (uint32_t)t, lane, cap);
        uint32_t hv = aload32(h_pk + (size_t)b2 * H_SZ + c1 + n2);  // own r-col h
        #pragma unroll
        for (int l = 2; l < 6; ++l) {
          const int kh = (lch[l] - 8) * 32 + kq * 8;
          const uint32_t* hp = h_pk + (size_t)bfrag * H_SZ + kh;
          u64 q0 = aload64(hp),     q1 = aload64(hp + 2);
          u64 q2 = aload64(hp + 4), q3 = aload64(hp + 6);
          uint32_t u[8] = {(uint32_t)q0, (uint32_t)(q0 >> 32), (uint32_t)q1, (uint32_t)(q1 >> 32),
                           (uint32_t)q2, (uint32_t)(q2 >> 32), (uint32_t)q3, (uint32_t)(q3 >> 32)};
          short8 hh, hl;
          #pragma unroll
          for (int j = 0; j < 8; ++j) { hh[j] = (short)(u[j] >> 16); hl[j] = (short)(u[j] & 0xffffu); }
          aZ = __builtin_amdgcn_mfma_f32_16x16x32_bf16(hh, wzh[l], aZ, 0, 0, 0);
          aZ = __builtin_amdgcn_mfma_f32_16x16x32_bf16(hl, wzh[l], aZ, 0, 0, 0);
          aZ = __builtin_amdgcn_mfma_f32_16x16x32_bf16(hh, wzl[l], aZ, 0, 0, 0);
          aR = __builtin_amdgcn_mfma_f32_16x16x32_bf16(hh, wrh_[l], aR, 0, 0, 0);
          aR = __builtin_amdgcn_mfma_f32_16x16x32_bf16(hl, wrh_[l], aR, 0, 0, 0);
          aR = __builtin_amdgcn_mfma_f32_16x16x32_bf16(hh, wrl_[l], aR, 0, 0, 0);
        }
        hval = unpackf(hv);
      } else {
        hval = h0[(size_t)b2 * H_SZ + c1 + n2];
        #pragma unroll
        for (int l = 2; l < 6; ++l) {
          const int kh = (lch[l] - 8) * 32 + kq * 8;
          const float* hp = h0 + (size_t)bfrag * H_SZ + kh;
          float4 f0 = *(const float4*)hp;
          float4 f1 = *(const float4*)(hp + 4);
          float f[8] = {f0.x, f0.y, f0.z, f0.w, f1.x, f1.y, f1.z, f1.w};
          short8 hh, hl;
          #pragma unroll
          for (int j = 0; j < 8; ++j) { short hi, lo; splitf(f[j], hi, lo); hh[j] = hi; hl[j] = lo; }
          aZ = __builtin_amdgcn_mfma_f32_16x16x32_bf16(hh, wzh[l], aZ, 0, 0, 0);
          aZ = __builtin_amdgcn_mfma_f32_16x16x32_bf16(hl, wzh[l], aZ, 0, 0, 0);
          aZ = __builtin_amdgcn_mfma_f32_16x16x32_bf16(hh, wzl[l], aZ, 0, 0, 0);
          aR = __builtin_amdgcn_mfma_f32_16x16x32_bf16(hh, wrh_[l], aR, 0, 0, 0);
          aR = __builtin_amdgcn_mfma_f32_16x16x32_bf16(hl, wrh_[l], aR, 0, 0, 0);
          aR = __builtin_amdgcn_mfma_f32_16x16x32_bf16(hh, wrl_[l], aR, 0, 0, 0);
        }
      }

      // ---- cross-wave K reduce, activate, publish z + rh ----
      #pragma unroll
      for (int r = 0; r < 4; ++r) {
        partTa[(wv * 4 + r) * 64 + lane] = aZ[r];
        partTb[(wv * 4 + r) * 64 + lane] = aR[r];
      }
      lds_barrier();
      {
        float sZ = partTa[(0 + wv) * 64 + lane] + partTa[(4 + wv) * 64 + lane]
                 + partTa[(8 + wv) * 64 + lane] + partTa[(12 + wv) * 64 + lane] + bzv;
        float sR = partTb[(0 + wv) * 64 + lane] + partTb[(4 + wv) * 64 + lane]
                 + partTb[(8 + wv) * 64 + lane] + partTb[(12 + wv) * 64 + lane] + brv;
        float zg = 1.f / (1.f + __expf(-sZ));
        float rg = 1.f / (1.f + __expf(-sR));
        astore32(z_pk  + (size_t)b2 * H_SZ + c1 + n2, __float_as_uint(zg));
        astore32(rh_pk + (size_t)b2 * H_SZ + c1 + n2, packf(rg * hval));
      }
      asm volatile("s_waitcnt vmcnt(0)" ::: "memory");   // ack: stores visible
      lds_barrier();                                     // all threads acked
      if (tid == 0) astore32(frh + wid, (uint32_t)(t + 1));
    }
  } else {
    // =================== CAND: 16 candidate cols ===================
    const int c2  = (wid - 32) * 16;
    const int col = c2 + n;

    short8 whh_[6], whl_[6];
    #pragma unroll
    for (int l = 0; l < 6; ++l) {
      #pragma unroll
      for (int j = 0; j < 8; ++j) {
        const int k = lch[l] * 32 + kq * 8 + j;
        short hi, lo;
        splitf(Wh[(size_t)k * H_SZ + col], hi, lo); whh_[l][j] = hi; whl_[l][j] = lo;
      }
    }
    const float bhv = bh[col];

    // own recurrent column: exact f32 register chain
    float hreg = h0[(size_t)b2 * H_SZ + c2 + n2];

    #pragma unroll 1
    for (int t = 0; t < T_STEPS; ++t) {
      // ---- x-part precompute (before poll) ----
      f32x4 acc = {0.f, 0.f, 0.f, 0.f};
      #pragma unroll
      for (int l = 0; l < 2; ++l) {
        const float* xp = x + ((size_t)t * B_SZ + bfrag) * D_SZ + lch[l] * 32 + kq * 8;
        float4 f0 = *(const float4*)xp;
        float4 f1 = *(const float4*)(xp + 4);
        float f[8] = {f0.x, f0.y, f0.z, f0.w, f1.x, f1.y, f1.z, f1.w};
        short8 xh, xl;
        #pragma unroll
        for (int j = 0; j < 8; ++j) { short hi, lo; splitf(f[j], hi, lo); xh[j] = hi; xl[j] = lo; }
        acc = __builtin_amdgcn_mfma_f32_16x16x32_bf16(xh, whh_[l], acc, 0, 0, 0);
        acc = __builtin_amdgcn_mfma_f32_16x16x32_bf16(xl, whh_[l], acc, 0, 0, 0);
        acc = __builtin_amdgcn_mfma_f32_16x16x32_bf16(xh, whl_[l], acc, 0, 0, 0);
      }

      // ---- wait for rh(t) (+z(t), same flag), gather, finish MFMAs ----
      poll_flags(frh, (uint32_t)(t + 1), lane, cap);
      uint32_t zu = aload32(z_pk + (size_t)b2 * H_SZ + c2 + n2);  // overlaps gather
      #pragma unroll
      for (int l = 2; l < 6; ++l) {
        const int kh = (lch[l] - 8) * 32 + kq * 8;
        const uint32_t* rp = rh_pk + (size_t)bfrag * H_SZ + kh;
        u64 q0 = aload64(rp),     q1 = aload64(rp + 2);
        u64 q2 = aload64(rp + 4), q3 = aload64(rp + 6);
        uint32_t u[8] = {(uint32_t)q0, (uint32_t)(q0 >> 32), (uint32_t)q1, (uint32_t)(q1 >> 32),
                         (uint32_t)q2, (uint32_t)(q2 >> 32), (uint32_t)q3, (uint32_t)(q3 >> 32)};
        short8 rh8, rl8;
        #pragma unroll
        for (int j = 0; j < 8; ++j) { rh8[j] = (short)(u[j] >> 16); rl8[j] = (short)(u[j] & 0xffffu); }
        acc = __builtin_amdgcn_mfma_f32_16x16x32_bf16(rh8, whh_[l], acc, 0, 0, 0);
        acc = __builtin_amdgcn_mfma_f32_16x16x32_bf16(rl8, whh_[l], acc, 0, 0, 0);
        acc = __builtin_amdgcn_mfma_f32_16x16x32_bf16(rh8, whl_[l], acc, 0, 0, 0);
      }

      // ---- reduce, tanh, blend (exact f32 chain), publish h ----
      #pragma unroll
      for (int r = 0; r < 4; ++r) partTa[(wv * 4 + r) * 64 + lane] = acc[r];
      lds_barrier();
      float hn;
      {
        float s = partTa[(0 + wv) * 64 + lane] + partTa[(4 + wv) * 64 + lane]
                + partTa[(8 + wv) * 64 + lane] + partTa[(12 + wv) * 64 + lane] + bhv;
        float e  = __expf(2.f * s);
        float ht = 1.f - 2.f / (e + 1.f);
        float zf = __uint_as_float(zu);
        hn = (1.f - zf) * hreg + zf * ht;
        hreg = hn;
        astore32(h_pk + (size_t)b2 * H_SZ + c2 + n2, packf(hn));
      }
      asm volatile("s_waitcnt vmcnt(0)" ::: "memory");   // ack: h visible
      lds_barrier();                                     // all threads acked
      if (tid == 0) astore32(fh + (wid - 32), (uint32_t)(t + 1));

      // HBM history write after release: off the critical path
      __builtin_nontemporal_store(hn, out + ((size_t)t * B_SZ + b2) * H_SZ + c2 + n2);
    }
  }
}

extern "C" void kernel_launch(void* const* d_in, const int* in_sizes, int n_in,
                              void* d_out, int out_size, void* d_ws, size_t ws_size,
                              hipStream_t stream) {
  const float* x  = (const float*)d_in[0];
  const float* h0 = (const float*)d_in[1];
  const float* Wz = (const float*)d_in[2];
  const float* bz = (const float*)d_in[3];
  const float* Wr = (const float*)d_in[4];
  const float* br = (const float*)d_in[5];
  const float* Wh = (const float*)d_in[6];
  const float* bh = (const float*)d_in[7];
  float* out = (float*)d_out;

  char* ws = (char*)d_ws;
  uint32_t* rh_flg = (uint32_t*)(ws + 0);        // [4][32] gate releases
  uint32_t* h_flg  = (uint32_t*)(ws + 2048);     // [4][32] cand releases
  uint32_t* h_pk   = (uint32_t*)(ws + 8192);            // [64][512] packed bf16 hi|lo
  uint32_t* rh_pk  = (uint32_t*)(ws + 8192 + 131072);   // [64][512] packed bf16 hi|lo
  uint32_t* z_pk   = (uint32_t*)(ws + 8192 + 262144);   // [64][512] f32 bits

  // zero only the flags; data planes are written before they are read
  hipMemsetAsync(d_ws, 0, 8192, stream);
  gru_roles<<<dim3(NGROUP * NWG), dim3(256), 0, stream>>>(
      x, h0, Wz, bz, Wr, br, Wh, bh, out,
      rh_flg, h_flg, h_pk, rh_pk, z_pk);
}

// Round 6
// 25407.350 us; speedup vs baseline: 1.6478x; 1.0105x over previous
//
#include <hip/hip_runtime.h>
#include <stdint.h>

// ---------------------------------------------------------------------------
// Persistent-grid GRU, fence-free cross-WG pipeline (R6 = R5 + pipelining).
//  - 4 batch-groups x 16 rows; GATE WGs (0-31) own 16 cols of z AND r;
//    CAND WGs (32-63) own 16 candidate cols + exact-f32 hreg chain.
//  - R6a: X REGISTER-PREFETCH one step ahead. x(t+1) loads are ISSUED at
//    the tail of step t (after flag raise, outside the critical vmcnt) and
//    CONSUMED next step in the hide region -> the cold x-stall that sat in
//    series with the poll is gone.
//  - R6b: ACK-HIDE. Between data-store issue and vmcnt(0), compute next
//    step's x-part MFMAs from prefetched registers (~500-700cy) so the
//    store-ack RTT overlaps useful work. Flag semantics unchanged.
//  - Transport byte-identical to R1/R5 (proven): packed (bf16hi<<16|lo)
//    u32 planes, f32 z-plane, per-thread vmcnt(0) ack before flag,
//    per-WG flags, lane-parallel polls, lgkmcnt-only barriers.
// ---------------------------------------------------------------------------

#define T_STEPS 2048
#define B_SZ    64
#define D_SZ    256
#define H_SZ    512
#define NGROUP  4
#define NWG     64
#define MB      16

typedef __attribute__((ext_vector_type(8))) short  short8;
typedef __attribute__((ext_vector_type(4))) float  f32x4;
typedef unsigned long long u64;

__device__ __forceinline__ unsigned short f2bf(float v) {
  uint32_t u = __float_as_uint(v);
  return (unsigned short)((u + 0x7fffu + ((u >> 16) & 1u)) >> 16);   // RTNE
}
__device__ __forceinline__ float bf2f(unsigned short h) {
  return __uint_as_float(((uint32_t)h) << 16);
}
__device__ __forceinline__ void splitf(float v, short& hi, short& lo) {
  unsigned short h = f2bf(v);
  hi = (short)h;
  lo = (short)f2bf(v - bf2f(h));
}
__device__ __forceinline__ uint32_t packf(float v) {
  unsigned short h = f2bf(v);
  unsigned short l = f2bf(v - bf2f(h));
  return ((uint32_t)h << 16) | (uint32_t)l;
}
__device__ __forceinline__ float unpackf(uint32_t p) {
  return __uint_as_float(p & 0xffff0000u) + __uint_as_float(p << 16);
}

__device__ __forceinline__ uint32_t aload32(const uint32_t* p) {
  return __hip_atomic_load(p, __ATOMIC_RELAXED, __HIP_MEMORY_SCOPE_AGENT);
}
__device__ __forceinline__ u64 aload64(const uint32_t* p) {
  return __hip_atomic_load((const unsigned long long*)p, __ATOMIC_RELAXED,
                           __HIP_MEMORY_SCOPE_AGENT);
}
__device__ __forceinline__ void astore32(uint32_t* p, uint32_t v) {
  __hip_atomic_store(p, v, __ATOMIC_RELAXED, __HIP_MEMORY_SCOPE_AGENT);
}

// raw barrier: LDS ordering only (vmcnt acks are done per-thread explicitly)
__device__ __forceinline__ void lds_barrier() {
  asm volatile("s_waitcnt lgkmcnt(0)" ::: "memory");
  __builtin_amdgcn_s_barrier();
}

// Lane-parallel poll over 32 per-WG flags (lanes 32-63 mirror 0-31).
__device__ __forceinline__ void poll_flags(const uint32_t* fl, uint32_t tgt,
                                           int lane, int& cap) {
  int guard = 0;
  for (;;) {
    uint32_t v = aload32(fl + (lane & 31));
    if (__all((int)(v >= tgt))) break;
    if (++guard > cap) { cap = 256; break; }   // degrade, never deadlock
    __builtin_amdgcn_s_sleep(1);
  }
}

__global__ void __launch_bounds__(256, 1)
gru_roles(const float* __restrict__ x, const float* __restrict__ h0,
          const float* __restrict__ Wz, const float* __restrict__ bz,
          const float* __restrict__ Wr, const float* __restrict__ br,
          const float* __restrict__ Wh, const float* __restrict__ bh,
          float* __restrict__ out,
          uint32_t* rh_flg, uint32_t* h_flg,
          uint32_t* h_pk, uint32_t* rh_pk, uint32_t* z_pk)
{
  __shared__ float partTa[16 * 64];
  __shared__ float partTb[16 * 64];

  const int tid  = threadIdx.x;
  const int wv   = tid >> 6;
  const int lane = tid & 63;
  const int blk  = blockIdx.x;
  const int g    = blk >> 6;           // contiguous grouping: dispatch-order safe
  const int wid  = blk & 63;
  const int m0   = g * MB;
  const bool isGate = (wid < 32);

  const int n     = lane & 15;         // MFMA fragment col / A-row-in-tile
  const int kq    = lane >> 4;         // k-quad
  const int bfrag = m0 + n;            // batch row this lane's A fragment holds
  const int m2    = kq * 4 + wv;       // C-layout row for this thread
  const int n2    = n;                 // C-layout col
  const int b2    = m0 + m2;

  uint32_t* frh = rh_flg + g * 32;     // raised by gate-WGs
  uint32_t* fh  = h_flg  + g * 32;     // raised by cand-WGs

  // chunk->wave map: wave wv owns x-chunks {2wv, 2wv+1}, h-chunks {8+4wv..11+4wv}
  int lch[6];
  lch[0] = 2 * wv; lch[1] = 2 * wv + 1;
  #pragma unroll
  for (int l = 2; l < 6; ++l) lch[l] = 8 + 4 * wv + (l - 2);

  int cap = 1 << 20;

  if (isGate) {
    // =================== GATE: 16 cols of z AND r ===================
    const int c1  = wid * 16;
    const int col = c1 + n;

    short8 wzh[6], wzl[6], wrh_[6], wrl_[6];
    #pragma unroll
    for (int l = 0; l < 6; ++l) {
      #pragma unroll
      for (int j = 0; j < 8; ++j) {
        const int k = lch[l] * 32 + kq * 8 + j;
        short hi, lo;
        splitf(Wz[(size_t)k * H_SZ + col], hi, lo); wzh[l][j] = hi; wzl[l][j] = lo;
        splitf(Wr[(size_t)k * H_SZ + col], hi, lo); wrh_[l][j] = hi; wrl_[l][j] = lo;
      }
    }
    const float bzv = bz[col];
    const float brv = br[col];

    // ---- prologue: x(0) -> accumulators (one-time stall); issue x(1) ----
    f32x4 aZc = {0.f, 0.f, 0.f, 0.f};
    f32x4 aRc = {0.f, 0.f, 0.f, 0.f};
    float4 xb[2][2];
    #pragma unroll
    for (int l = 0; l < 2; ++l) {
      const float* xp = x + (size_t)bfrag * D_SZ + lch[l] * 32 + kq * 8;
      float4 f0 = *(const float4*)xp;
      float4 f1 = *(const float4*)(xp + 4);
      float f[8] = {f0.x, f0.y, f0.z, f0.w, f1.x, f1.y, f1.z, f1.w};
      short8 xh, xl;
      #pragma unroll
      for (int j = 0; j < 8; ++j) { short hi, lo; splitf(f[j], hi, lo); xh[j] = hi; xl[j] = lo; }
      aZc = __builtin_amdgcn_mfma_f32_16x16x32_bf16(xh, wzh[l], aZc, 0, 0, 0);
      aZc = __builtin_amdgcn_mfma_f32_16x16x32_bf16(xl, wzh[l], aZc, 0, 0, 0);
      aZc = __builtin_amdgcn_mfma_f32_16x16x32_bf16(xh, wzl[l], aZc, 0, 0, 0);
      aRc = __builtin_amdgcn_mfma_f32_16x16x32_bf16(xh, wrh_[l], aRc, 0, 0, 0);
      aRc = __builtin_amdgcn_mfma_f32_16x16x32_bf16(xl, wrh_[l], aRc, 0, 0, 0);
      aRc = __builtin_amdgcn_mfma_f32_16x16x32_bf16(xh, wrl_[l], aRc, 0, 0, 0);
    }
    #pragma unroll
    for (int l = 0; l < 2; ++l) {   // issue x(1) loads (consumed next step)
      const float* xp = x + ((size_t)1 * B_SZ + bfrag) * D_SZ + lch[l] * 32 + kq * 8;
      xb[l][0] = *(const float4*)xp;
      xb[l][1] = *(const float4*)(xp + 4);
    }

    #pragma unroll 1
    for (int t = 0; t < T_STEPS; ++t) {
      // ---- wait for h(t-1), gather 4 h-chunks, finish MFMAs ----
      float hval;
      if (t > 0) {
        poll_flags(fh, (uint32_t)t, lane, cap);
        uint32_t hv = aload32(h_pk + (size_t)b2 * H_SZ + c1 + n2);  // own r-col h
        #pragma unroll
        for (int l = 2; l < 6; ++l) {
          const int kh = (lch[l] - 8) * 32 + kq * 8;
          const uint32_t* hp = h_pk + (size_t)bfrag * H_SZ + kh;
          u64 q0 = aload64(hp),     q1 = aload64(hp + 2);
          u64 q2 = aload64(hp + 4), q3 = aload64(hp + 6);
          uint32_t u[8] = {(uint32_t)q0, (uint32_t)(q0 >> 32), (uint32_t)q1, (uint32_t)(q1 >> 32),
                           (uint32_t)q2, (uint32_t)(q2 >> 32), (uint32_t)q3, (uint32_t)(q3 >> 32)};
          short8 hh, hl;
          #pragma unroll
          for (int j = 0; j < 8; ++j) { hh[j] = (short)(u[j] >> 16); hl[j] = (short)(u[j] & 0xffffu); }
          aZc = __builtin_amdgcn_mfma_f32_16x16x32_bf16(hh, wzh[l], aZc, 0, 0, 0);
          aZc = __builtin_amdgcn_mfma_f32_16x16x32_bf16(hl, wzh[l], aZc, 0, 0, 0);
          aZc = __builtin_amdgcn_mfma_f32_16x16x32_bf16(hh, wzl[l], aZc, 0, 0, 0);
          aRc = __builtin_amdgcn_mfma_f32_16x16x32_bf16(hh, wrh_[l], aRc, 0, 0, 0);
          aRc = __builtin_amdgcn_mfma_f32_16x16x32_bf16(hl, wrh_[l], aRc, 0, 0, 0);
          aRc = __builtin_amdgcn_mfma_f32_16x16x32_bf16(hh, wrl_[l], aRc, 0, 0, 0);
        }
        hval = unpackf(hv);
      } else {
        hval = h0[(size_t)b2 * H_SZ + c1 + n2];
        #pragma unroll
        for (int l = 2; l < 6; ++l) {
          const int kh = (lch[l] - 8) * 32 + kq * 8;
          const float* hp = h0 + (size_t)bfrag * H_SZ + kh;
          float4 f0 = *(const float4*)hp;
          float4 f1 = *(const float4*)(hp + 4);
          float f[8] = {f0.x, f0.y, f0.z, f0.w, f1.x, f1.y, f1.z, f1.w};
          short8 hh, hl;
          #pragma unroll
          for (int j = 0; j < 8; ++j) { short hi, lo; splitf(f[j], hi, lo); hh[j] = hi; hl[j] = lo; }
          aZc = __builtin_amdgcn_mfma_f32_16x16x32_bf16(hh, wzh[l], aZc, 0, 0, 0);
          aZc = __builtin_amdgcn_mfma_f32_16x16x32_bf16(hl, wzh[l], aZc, 0, 0, 0);
          aZc = __builtin_amdgcn_mfma_f32_16x16x32_bf16(hh, wzl[l], aZc, 0, 0, 0);
          aRc = __builtin_amdgcn_mfma_f32_16x16x32_bf16(hh, wrh_[l], aRc, 0, 0, 0);
          aRc = __builtin_amdgcn_mfma_f32_16x16x32_bf16(hl, wrh_[l], aRc, 0, 0, 0);
          aRc = __builtin_amdgcn_mfma_f32_16x16x32_bf16(hh, wrl_[l], aRc, 0, 0, 0);
        }
      }

      // ---- cross-wave K reduce, activate, publish z + rh (issue) ----
      #pragma unroll
      for (int r = 0; r < 4; ++r) {
        partTa[(wv * 4 + r) * 64 + lane] = aZc[r];
        partTb[(wv * 4 + r) * 64 + lane] = aRc[r];
      }
      lds_barrier();
      {
        float sZ = partTa[(0 + wv) * 64 + lane] + partTa[(4 + wv) * 64 + lane]
                 + partTa[(8 + wv) * 64 + lane] + partTa[(12 + wv) * 64 + lane] + bzv;
        float sR = partTb[(0 + wv) * 64 + lane] + partTb[(4 + wv) * 64 + lane]
                 + partTb[(8 + wv) * 64 + lane] + partTb[(12 + wv) * 64 + lane] + brv;
        float zg = 1.f / (1.f + __expf(-sZ));
        float rg = 1.f / (1.f + __expf(-sR));
        astore32(z_pk  + (size_t)b2 * H_SZ + c1 + n2, __float_as_uint(zg));
        astore32(rh_pk + (size_t)b2 * H_SZ + c1 + n2, packf(rg * hval));
      }

      // ---- ack-hide: next step's x-part MFMAs from prefetched regs ----
      f32x4 aZn = {0.f, 0.f, 0.f, 0.f};
      f32x4 aRn = {0.f, 0.f, 0.f, 0.f};
      if (t + 1 < T_STEPS) {
        #pragma unroll
        for (int l = 0; l < 2; ++l) {
          float f[8] = {xb[l][0].x, xb[l][0].y, xb[l][0].z, xb[l][0].w,
                        xb[l][1].x, xb[l][1].y, xb[l][1].z, xb[l][1].w};
          short8 xh, xl;
          #pragma unroll
          for (int j = 0; j < 8; ++j) { short hi, lo; splitf(f[j], hi, lo); xh[j] = hi; xl[j] = lo; }
          aZn = __builtin_amdgcn_mfma_f32_16x16x32_bf16(xh, wzh[l], aZn, 0, 0, 0);
          aZn = __builtin_amdgcn_mfma_f32_16x16x32_bf16(xl, wzh[l], aZn, 0, 0, 0);
          aZn = __builtin_amdgcn_mfma_f32_16x16x32_bf16(xh, wzl[l], aZn, 0, 0, 0);
          aRn = __builtin_amdgcn_mfma_f32_16x16x32_bf16(xh, wrh_[l], aRn, 0, 0, 0);
          aRn = __builtin_amdgcn_mfma_f32_16x16x32_bf16(xl, wrh_[l], aRn, 0, 0, 0);
          aRn = __builtin_amdgcn_mfma_f32_16x16x32_bf16(xh, wrl_[l], aRn, 0, 0, 0);
        }
      }

      asm volatile("s_waitcnt vmcnt(0)" ::: "memory");   // ack: z/rh visible
      lds_barrier();                                     // all threads acked
      if (tid == 0) astore32(frh + wid, (uint32_t)(t + 1));

      // ---- tail: issue x(t+2) loads (outside critical vmcnt) ----
      if (t + 2 < T_STEPS) {
        #pragma unroll
        for (int l = 0; l < 2; ++l) {
          const float* xp = x + ((size_t)(t + 2) * B_SZ + bfrag) * D_SZ + lch[l] * 32 + kq * 8;
          xb[l][0] = *(const float4*)xp;
          xb[l][1] = *(const float4*)(xp + 4);
        }
      }
      aZc = aZn; aRc = aRn;
    }
  } else {
    // =================== CAND: 16 candidate cols ===================
    const int c2  = (wid - 32) * 16;
    const int col = c2 + n;

    short8 whh_[6], whl_[6];
    #pragma unroll
    for (int l = 0; l < 6; ++l) {
      #pragma unroll
      for (int j = 0; j < 8; ++j) {
        const int k = lch[l] * 32 + kq * 8 + j;
        short hi, lo;
        splitf(Wh[(size_t)k * H_SZ + col], hi, lo); whh_[l][j] = hi; whl_[l][j] = lo;
      }
    }
    const float bhv = bh[col];

    // own recurrent column: exact f32 register chain
    float hreg = h0[(size_t)b2 * H_SZ + c2 + n2];

    // ---- prologue: x(0) -> accumulator (one-time stall); issue x(1) ----
    f32x4 acc = {0.f, 0.f, 0.f, 0.f};
    float4 xb[2][2];
    #pragma unroll
    for (int l = 0; l < 2; ++l) {
      const float* xp = x + (size_t)bfrag * D_SZ + lch[l] * 32 + kq * 8;
      float4 f0 = *(const float4*)xp;
      float4 f1 = *(const float4*)(xp + 4);
      float f[8] = {f0.x, f0.y, f0.z, f0.w, f1.x, f1.y, f1.z, f1.w};
      short8 xh, xl;
      #pragma unroll
      for (int j = 0; j < 8; ++j) { short hi, lo; splitf(f[j], hi, lo); xh[j] = hi; xl[j] = lo; }
      acc = __builtin_amdgcn_mfma_f32_16x16x32_bf16(xh, whh_[l], acc, 0, 0, 0);
      acc = __builtin_amdgcn_mfma_f32_16x16x32_bf16(xl, whh_[l], acc, 0, 0, 0);
      acc = __builtin_amdgcn_mfma_f32_16x16x32_bf16(xh, whl_[l], acc, 0, 0, 0);
    }
    #pragma unroll
    for (int l = 0; l < 2; ++l) {   // issue x(1) loads
      const float* xp = x + ((size_t)1 * B_SZ + bfrag) * D_SZ + lch[l] * 32 + kq * 8;
      xb[l][0] = *(const float4*)xp;
      xb[l][1] = *(const float4*)(xp + 4);
    }

    #pragma unroll 1
    for (int t = 0; t < T_STEPS; ++t) {
      // ---- wait for rh(t) (+z(t), same flag), gather, finish MFMAs ----
      poll_flags(frh, (uint32_t)(t + 1), lane, cap);
      uint32_t zu = aload32(z_pk + (size_t)b2 * H_SZ + c2 + n2);  // overlaps gather
      #pragma unroll
      for (int l = 2; l < 6; ++l) {
        const int kh = (lch[l] - 8) * 32 + kq * 8;
        const uint32_t* rp = rh_pk + (size_t)bfrag * H_SZ + kh;
        u64 q0 = aload64(rp),     q1 = aload64(rp + 2);
        u64 q2 = aload64(rp + 4), q3 = aload64(rp + 6);
        uint32_t u[8] = {(uint32_t)q0, (uint32_t)(q0 >> 32), (uint32_t)q1, (uint32_t)(q1 >> 32),
                         (uint32_t)q2, (uint32_t)(q2 >> 32), (uint32_t)q3, (uint32_t)(q3 >> 32)};
        short8 rh8, rl8;
        #pragma unroll
        for (int j = 0; j < 8; ++j) { rh8[j] = (short)(u[j] >> 16); rl8[j] = (short)(u[j] & 0xffffu); }
        acc = __builtin_amdgcn_mfma_f32_16x16x32_bf16(rh8, whh_[l], acc, 0, 0, 0);
        acc = __builtin_amdgcn_mfma_f32_16x16x32_bf16(rl8, whh_[l], acc, 0, 0, 0);
        acc = __builtin_amdgcn_mfma_f32_16x16x32_bf16(rh8, whl_[l], acc, 0, 0, 0);
      }

      // ---- reduce, tanh, blend (exact f32 chain), publish h (issue) ----
      #pragma unroll
      for (int r = 0; r < 4; ++r) partTa[(wv * 4 + r) * 64 + lane] = acc[r];
      lds_barrier();
      float hn;
      {
        float s = partTa[(0 + wv) * 64 + lane] + partTa[(4 + wv) * 64 + lane]
                + partTa[(8 + wv) * 64 + lane] + partTa[(12 + wv) * 64 + lane] + bhv;
        float e  = __expf(2.f * s);
        float ht = 1.f - 2.f / (e + 1.f);
        float zf = __uint_as_float(zu);
        hn = (1.f - zf) * hreg + zf * ht;
        hreg = hn;
        astore32(h_pk + (size_t)b2 * H_SZ + c2 + n2, packf(hn));
      }

      // ---- ack-hide: next step's x-part MFMAs from prefetched regs ----
      f32x4 accn = {0.f, 0.f, 0.f, 0.f};
      if (t + 1 < T_STEPS) {
        #pragma unroll
        for (int l = 0; l < 2; ++l) {
          float f[8] = {xb[l][0].x, xb[l][0].y, xb[l][0].z, xb[l][0].w,
                        xb[l][1].x, xb[l][1].y, xb[l][1].z, xb[l][1].w};
          short8 xh, xl;
          #pragma unroll
          for (int j = 0; j < 8; ++j) { short hi, lo; splitf(f[j], hi, lo); xh[j] = hi; xl[j] = lo; }
          accn = __builtin_amdgcn_mfma_f32_16x16x32_bf16(xh, whh_[l], accn, 0, 0, 0);
          accn = __builtin_amdgcn_mfma_f32_16x16x32_bf16(xl, whh_[l], accn, 0, 0, 0);
          accn = __builtin_amdgcn_mfma_f32_16x16x32_bf16(xh, whl_[l], accn, 0, 0, 0);
        }
      }

      asm volatile("s_waitcnt vmcnt(0)" ::: "memory");   // ack: h visible
      lds_barrier();                                     // all threads acked
      if (tid == 0) astore32(fh + (wid - 32), (uint32_t)(t + 1));

      // ---- tail: issue x(t+2); out-store off critical path ----
      if (t + 2 < T_STEPS) {
        #pragma unroll
        for (int l = 0; l < 2; ++l) {
          const float* xp = x + ((size_t)(t + 2) * B_SZ + bfrag) * D_SZ + lch[l] * 32 + kq * 8;
          xb[l][0] = *(const float4*)xp;
          xb[l][1] = *(const float4*)(xp + 4);
        }
      }
      __builtin_nontemporal_store(hn, out + ((size_t)t * B_SZ + b2) * H_SZ + c2 + n2);
      acc = accn;
    }
  }
}

extern "C" void kernel_launch(void* const* d_in, const int* in_sizes, int n_in,
                              void* d_out, int out_size, void* d_ws, size_t ws_size,
                              hipStream_t stream) {
  const float* x  = (const float*)d_in[0];
  const float* h0 = (const float*)d_in[1];
  const float* Wz = (const float*)d_in[2];
  const float* bz = (const float*)d_in[3];
  const float* Wr = (const float*)d_in[4];
  const float* br = (const float*)d_in[5];
  const float* Wh = (const float*)d_in[6];
  const float* bh = (const float*)d_in[7];
  float* out = (float*)d_out;

  char* ws = (char*)d_ws;
  uint32_t* rh_flg = (uint32_t*)(ws + 0);        // [4][32] gate releases
  uint32_t* h_flg  = (uint32_t*)(ws + 2048);     // [4][32] cand releases
  uint32_t* h_pk   = (uint32_t*)(ws + 8192);            // [64][512] packed bf16 hi|lo
  uint32_t* rh_pk  = (uint32_t*)(ws + 8192 + 131072);   // [64][512] packed bf16 hi|lo
  uint32_t* z_pk   = (uint32_t*)(ws + 8192 + 262144);   // [64][512] f32 bits

  // zero only the flags; data planes are written before they are read
  hipMemsetAsync(d_ws, 0, 8192, stream);
  gru_roles<<<dim3(NGROUP * NWG), dim3(256), 0, stream>>>(
      x, h0, Wz, bz, Wr, br, Wh, bh, out,
      rh_flg, h_flg, h_pk, rh_pk, z_pk);
}